// Round 7
// baseline (589.340 us; speedup 1.0000x reference)
//
#include <hip/hip_runtime.h>
#include <hip/hip_bf16.h>

#define NUSERS  50000
#define NNODES  100000
#define NEDGES  3200000
#define DIM     64
#define OSTRIDE 256   // output row stride: (3+1)*64
#define NBUCK   391   // ceil(NNODES/256) buckets of 256 rows
#define EPB     8192  // edges per block in bucketing kernels
#define NPBLK   391   // ceil(NEDGES/EPB)

typedef unsigned short u16;
typedef unsigned int u32;
typedef __attribute__((ext_vector_type(8))) short bf16x8;
typedef __attribute__((ext_vector_type(4))) float f32x4;

__device__ __forceinline__ float us2f(u16 u) {
    return __uint_as_float((u32)u << 16);
}
__device__ __forceinline__ u16 f2b(float f) {           // f32 -> bf16 RNE bits
    u32 u = __float_as_uint(f);
    return (u16)((u + 0x7fffu + ((u >> 16) & 1u)) >> 16);
}

// ---------------------------------------------------------------------------
// out[:, 0:64] = concat(ue, ie) (fp32); ego planes (bf16, [q][node][16])
// ---------------------------------------------------------------------------
__global__ __launch_bounds__(256) void init_ego(const float* __restrict__ ue,
                                                const float* __restrict__ ie,
                                                float* __restrict__ out,
                                                u32*   __restrict__ egoP) {
    int gid = blockIdx.x * 256 + threadIdx.x;
    if (gid >= NNODES * 16) return;
    int node = gid >> 4, c = gid & 15;
    float4 v = (node < NUSERS)
        ? ((const float4*)ue)[node * 16 + c]
        : ((const float4*)ie)[(size_t)(node - NUSERS) * 16 + c];
    ((float4*)(out + (size_t)node * OSTRIDE))[c] = v;
    int p = c >> 2;                                  // plane (dims 16p..16p+15)
    u32* d = egoP + (size_t)p * NNODES * 8 + (size_t)node * 8 + 2 * (c & 3);
    d[0] = (u32)f2b(v.x) | ((u32)f2b(v.y) << 16);
    d[1] = (u32)f2b(v.z) | ((u32)f2b(v.w) << 16);
}

// ---------------------------------------------------------------------------
// Bucketed counting sort (R4, proven): count -> scan -> place -> to_csr
// ---------------------------------------------------------------------------
__global__ __launch_bounds__(256) void bucket_count(const int* __restrict__ rows,
                                                    int* __restrict__ bcount) {
    __shared__ int lh[NBUCK];
    int tid = threadIdx.x;
    for (int i = tid; i < NBUCK; i += 256) lh[i] = 0;
    __syncthreads();
    int e0 = blockIdx.x * EPB, e1 = min(e0 + EPB, NEDGES);
    for (int e = e0 + tid; e < e1; e += 256)
        atomicAdd(&lh[rows[e] >> 8], 1);
    __syncthreads();
    for (int i = tid; i < NBUCK; i += 256)
        if (lh[i]) atomicAdd(&bcount[i], lh[i]);
}

__global__ __launch_bounds__(512) void bucket_scan(const int* __restrict__ bcount,
                                                   int* __restrict__ bbase,
                                                   int* __restrict__ bcursor,
                                                   int* __restrict__ rs) {
    __shared__ int sc[512];
    int tid = threadIdx.x;
    int v = (tid < NBUCK) ? bcount[tid] : 0;
    sc[tid] = v;
    __syncthreads();
    for (int off = 1; off < 512; off <<= 1) {
        int t = (tid >= off) ? sc[tid - off] : 0;
        __syncthreads();
        sc[tid] += t;
        __syncthreads();
    }
    if (tid < NBUCK) {
        int excl = sc[tid] - v;
        bbase[tid] = excl;
        bcursor[tid] = excl;
    }
    if (tid == 0) { bbase[NBUCK] = NEDGES; rs[NNODES] = NEDGES; }
}

__global__ __launch_bounds__(256) void bucket_place(const int*   __restrict__ rows,
                                                    const int*   __restrict__ cols,
                                                    const float* __restrict__ vals,
                                                    int*  __restrict__ bcursor,
                                                    int2* __restrict__ tmp) {
    __shared__ int lh[NBUCK];
    int tid = threadIdx.x;
    for (int i = tid; i < NBUCK; i += 256) lh[i] = 0;
    __syncthreads();
    int e0 = blockIdx.x * EPB, e1 = min(e0 + EPB, NEDGES);
    for (int e = e0 + tid; e < e1; e += 256)
        atomicAdd(&lh[rows[e] >> 8], 1);
    __syncthreads();
    for (int i = tid; i < NBUCK; i += 256) {
        int c = lh[i];
        lh[i] = c ? atomicAdd(&bcursor[i], c) : 0;
    }
    __syncthreads();
    for (int e = e0 + tid; e < e1; e += 256) {
        int r = rows[e];
        int p = atomicAdd(&lh[r >> 8], 1);
        tmp[p] = make_int2(((r & 255) << 20) | cols[e], (int)f2b(vals[e]));
    }
}

__global__ __launch_bounds__(256) void bucket_to_csr(const int*  __restrict__ bbase,
                                                     const int2* __restrict__ tmp,
                                                     int* __restrict__ rs,
                                                     int* __restrict__ colS,
                                                     u16* __restrict__ valS) {
    __shared__ int rcnt[256];
    __shared__ int cur[256];
    int b = blockIdx.x, tid = threadIdx.x;
    int j0 = bbase[b], j1 = bbase[b + 1];
    rcnt[tid] = 0;
    __syncthreads();
    for (int j = j0 + tid; j < j1; j += 256)
        atomicAdd(&rcnt[tmp[j].x >> 20], 1);
    __syncthreads();
    int own = rcnt[tid];
    for (int off = 1; off < 256; off <<= 1) {
        int t = (tid >= off) ? rcnt[tid - off] : 0;
        __syncthreads();
        rcnt[tid] += t;
        __syncthreads();
    }
    int start = j0 + rcnt[tid] - own;
    int row = b * 256 + tid;
    if (row < NNODES) rs[row] = start;
    cur[tid] = start;
    __syncthreads();
    for (int j = j0 + tid; j < j1; j += 256) {
        int2 t2 = tmp[j];
        int p = atomicAdd(&cur[t2.x >> 20], 1);
        colS[p] = t2.x & 0xFFFFF;
        valS[p] = (u16)t2.y;
    }
}

// ---------------------------------------------------------------------------
// Pre-convert weights to fragment-ordered bf16 (once per call, 3 layers)
// layout idx = [s(2)][t(4)][lane(64)][e(8)], k=32s+8(l>>4)+e, n=16t+(l&15)
// ---------------------------------------------------------------------------
__global__ __launch_bounds__(256) void weights_prep(const float* __restrict__ Wg,
                                                    const float* __restrict__ Wb,
                                                    u16* __restrict__ wpre) {
    int layer = blockIdx.y;
    int idx = blockIdx.x * 256 + threadIdx.x;   // 0..8191
    int e = idx & 7, l = (idx >> 3) & 63, t = (idx >> 9) & 3, s = idx >> 11;
    int k = 32 * s + 8 * (l >> 4) + e;
    int n = 16 * t + (l & 15);
    float wv = (k < 64) ? Wg[layer * 4096 + k * 64 + n]
                        : Wb[layer * 4096 + (k - 64) * 64 + n];
    wpre[layer * 8192 + idx] = f2b(wv);
}

// ---------------------------------------------------------------------------
// SpMM, XCD-steered dim-plane version.
//   bid&7 -> XCD (round-robin dispatch);  q = (bid&7)>>1  -> plane 3.2MB,
//   resident in that XCD pair's L2. 8 lanes per edge (dword = 2 dims),
//   8 edge-slots per wave, shfl_xor reduce, lanes 0-7 write 32B.
// ---------------------------------------------------------------------------
__global__ __launch_bounds__(256) void spmm(const int* __restrict__ rs,
                                            const int* __restrict__ colS,
                                            const u16* __restrict__ valS,
                                            const u32* __restrict__ egoP,
                                            u32*       __restrict__ side32) {
    int bid = blockIdx.x;
    int xcd = bid & 7;
    int q = xcd >> 1;
    int chunk = ((bid >> 3) << 1) + (xcd & 1);
    int row0 = chunk * 32;
    if (row0 >= NNODES) return;

    int tid = threadIdx.x, w = tid >> 6, lane = tid & 63;
    int slot = lane >> 3, dw = lane & 7;
    const u32* plane = egoP + (size_t)q * NNODES * 8;

    #pragma unroll
    for (int rr = 0; rr < 8; ++rr) {
        int row = row0 + w * 8 + rr;
        int j0 = rs[row], j1 = rs[row + 1];
        float alo = 0.f, ahi = 0.f;
        int jb = j0;
        for (; jb + 16 <= j1; jb += 16) {           // 16 edges, 2 gathers in flight
            int jA = jb + slot, jB = jA + 8;
            int cA = colS[jA], cB = colS[jB];
            float vA = us2f(valS[jA]), vB = us2f(valS[jB]);
            u32 gA = plane[(size_t)cA * 8 + dw];
            u32 gB = plane[(size_t)cB * 8 + dw];
            alo = fmaf(vA, __uint_as_float(gA << 16), alo);
            ahi = fmaf(vA, __uint_as_float(gA & 0xFFFF0000u), ahi);
            alo = fmaf(vB, __uint_as_float(gB << 16), alo);
            ahi = fmaf(vB, __uint_as_float(gB & 0xFFFF0000u), ahi);
        }
        for (; jb < j1; jb += 8) {
            int j = jb + slot;
            if (j < j1) {
                int c = colS[j];
                float v = us2f(valS[j]);
                u32 g = plane[(size_t)c * 8 + dw];
                alo = fmaf(v, __uint_as_float(g << 16), alo);
                ahi = fmaf(v, __uint_as_float(g & 0xFFFF0000u), ahi);
            }
        }
        alo += __shfl_xor(alo, 8, 64);  ahi += __shfl_xor(ahi, 8, 64);
        alo += __shfl_xor(alo, 16, 64); ahi += __shfl_xor(ahi, 16, 64);
        alo += __shfl_xor(alo, 32, 64); ahi += __shfl_xor(ahi, 32, 64);
        if (lane < 8)
            side32[(size_t)row * 32 + q * 8 + lane] =
                (u32)f2b(alo) | ((u32)f2b(ahi) << 16);
    }
}

// ---------------------------------------------------------------------------
// Dense layer via MFMA: C[N,64] = [side | ego_raw*side] @ [Wg; Wb] + bsum,
// leaky-relu; raw fp32 -> out col (layer+1); bf16 -> ego planes.
// ---------------------------------------------------------------------------
__global__ __launch_bounds__(256) void dense_mfma(const u16* __restrict__ side,
                                                  float*     __restrict__ out,
                                                  u16*       __restrict__ egoP,
                                                  const u16* __restrict__ wpre,
                                                  const float* __restrict__ bg,
                                                  const float* __restrict__ bb,
                                                  int layer) {
    __shared__ u16 bfr[8192];
    __shared__ float lbias[64];

    int tid = threadIdx.x;
    {   // straight 16KB copy of pre-converted weights
        const uint4* src = (const uint4*)(wpre + layer * 8192);
        uint4* dst = (uint4*)bfr;
        #pragma unroll
        for (int i = 0; i < 4; ++i) dst[tid + 256 * i] = src[tid + 256 * i];
    }
    if (tid < 64) lbias[tid] = bg[layer * 64 + tid] + bb[layer * 64 + tid];
    __syncthreads();

    int w = tid >> 6, lane = tid & 63;
    int g = lane >> 4, m = lane & 15;
    int rb = blockIdx.x * 64 + w * 16;
    int rowc = min(rb + m, NNODES - 1);

    bf16x8 sf0 = *(const bf16x8*)(side + (size_t)rowc * DIM + g * 8);
    bf16x8 sf1 = *(const bf16x8*)(side + (size_t)rowc * DIM + 32 + g * 8);
    const float* erow = out + (size_t)rowc * OSTRIDE + layer * DIM;
    float4 e0a = *(const float4*)(erow + 8 * g);
    float4 e0b = *(const float4*)(erow + 8 * g + 4);
    float4 e1a = *(const float4*)(erow + 32 + 8 * g);
    float4 e1b = *(const float4*)(erow + 32 + 8 * g + 4);
    float ev0[8] = {e0a.x, e0a.y, e0a.z, e0a.w, e0b.x, e0b.y, e0b.z, e0b.w};
    float ev1[8] = {e1a.x, e1a.y, e1a.z, e1a.w, e1b.x, e1b.y, e1b.z, e1b.w};
    bf16x8 pf0, pf1;
    #pragma unroll
    for (int e = 0; e < 8; ++e) {
        pf0[e] = (short)f2b(us2f((u16)sf0[e]) * ev0[e]);
        pf1[e] = (short)f2b(us2f((u16)sf1[e]) * ev1[e]);
    }

    const bf16x8* B = (const bf16x8*)bfr;
    f32x4 acc[4];
    #pragma unroll
    for (int t = 0; t < 4; ++t) {
        acc[t] = (f32x4){0.f, 0.f, 0.f, 0.f};
        acc[t] = __builtin_amdgcn_mfma_f32_16x16x32_bf16(sf0, B[(0 * 4 + t) * 64 + lane], acc[t], 0, 0, 0);
        acc[t] = __builtin_amdgcn_mfma_f32_16x16x32_bf16(sf1, B[(1 * 4 + t) * 64 + lane], acc[t], 0, 0, 0);
        acc[t] = __builtin_amdgcn_mfma_f32_16x16x32_bf16(pf0, B[(2 * 4 + t) * 64 + lane], acc[t], 0, 0, 0);
        acc[t] = __builtin_amdgcn_mfma_f32_16x16x32_bf16(pf1, B[(3 * 4 + t) * 64 + lane], acc[t], 0, 0, 0);
    }

    // D col = 16t+m (plane t), row = rb + 4g + r
    #pragma unroll
    for (int t = 0; t < 4; ++t) {
        float bsv = lbias[16 * t + m];
        u16* plane = egoP + (size_t)t * NNODES * 16;
        #pragma unroll
        for (int r = 0; r < 4; ++r) {
            int rw = rb + 4 * g + r;
            if (rw < NNODES) {
                float v = acc[t][r] + bsv;
                v = v >= 0.f ? v : 0.2f * v;
                out[(size_t)rw * OSTRIDE + (layer + 1) * DIM + 16 * t + m] = v;
                plane[(size_t)rw * 16 + m] = f2b(v);
            }
        }
    }
}

// ---------------------------------------------------------------------------
// L2-normalize the three layer column blocks (cols 64..255)
// ---------------------------------------------------------------------------
__global__ __launch_bounds__(256) void normalize_cols(float* __restrict__ out) {
    int node = blockIdx.x * 4 + (threadIdx.x >> 6);
    int lane = threadIdx.x & 63;
    float* p = out + (size_t)node * OSTRIDE + DIM;
    #pragma unroll
    for (int b = 0; b < 3; ++b) {
        float v = p[b * 64 + lane];
        float ss = v * v;
        #pragma unroll
        for (int m = 1; m < 64; m <<= 1) ss += __shfl_xor(ss, m, 64);
        p[b * 64 + lane] = v / fmaxf(sqrtf(ss), 1e-12f);
    }
}

// ---------------------------------------------------------------------------
extern "C" void kernel_launch(void* const* d_in, const int* in_sizes, int n_in,
                              void* d_out, int out_size, void* d_ws, size_t ws_size,
                              hipStream_t stream) {
    const float* ue   = (const float*)d_in[0];
    const float* ie   = (const float*)d_in[1];
    const float* Wg   = (const float*)d_in[2];
    const float* bg   = (const float*)d_in[3];
    const float* Wb   = (const float*)d_in[4];
    const float* bb   = (const float*)d_in[5];
    const int*   rows = (const int*)d_in[6];
    const int*   cols = (const int*)d_in[7];
    const float* vals = (const float*)d_in[8];
    float* out = (float*)d_out;

    // ws: rs[N+1] | colS[E] | valS[E] | bucket meta | wpre[3*8192] |
    //     tmp[E] int2 (25.6MB)  aliased after CSR build by:
    //     egoP (4 planes x N x 16 u16 = 12.8MB) + side (N x 64 u16 = 12.8MB)
    int* rs   = (int*)d_ws;
    int* colS = rs + NNODES + 1;
    u16* valS = (u16*)(colS + NEDGES);
    int* bcount  = (int*)(valS + NEDGES);
    int* bbase   = bcount + NBUCK;
    int* bcursor = bbase + NBUCK + 1;
    u16* wpre    = (u16*)(bcursor + NBUCK);
    uintptr_t tp = ((uintptr_t)(wpre + 3 * 8192) + 15) & ~(uintptr_t)15;
    int2* tmp = (int2*)tp;
    u32*  egoP = (u32*)tp;                              // 12.8 MB (4 planes)
    u16*  side = (u16*)(egoP + (size_t)NNODES * 32);    // 12.8 MB

    hipMemsetAsync(bcount, 0, NBUCK * sizeof(int), stream);
    bucket_count<<<NPBLK, 256, 0, stream>>>(rows, bcount);
    bucket_scan<<<1, 512, 0, stream>>>(bcount, bbase, bcursor, rs);
    bucket_place<<<NPBLK, 256, 0, stream>>>(rows, cols, vals, bcursor, tmp);
    bucket_to_csr<<<NBUCK, 256, 0, stream>>>(bbase, tmp, rs, colS, valS);

    weights_prep<<<dim3(32, 3), 256, 0, stream>>>(Wg, Wb, wpre);

    // init_ego AFTER the sort: egoP aliases tmp
    init_ego<<<(NNODES * 16 + 255) / 256, 256, 0, stream>>>(ue, ie, out, egoP);

    for (int l = 0; l < 3; ++l) {
        spmm<<<1563 * 8, 256, 0, stream>>>(rs, colS, valS, egoP, (u32*)side);
        dense_mfma<<<(NNODES + 63) / 64, 256, 0, stream>>>(side, out, (u16*)egoP,
                                                           wpre, bg, bb, l);
    }

    normalize_cols<<<NNODES / 4, 256, 0, stream>>>(out);
}

// Round 8
// 477.352 us; speedup vs baseline: 1.2346x; 1.2346x over previous
//
#include <hip/hip_runtime.h>
#include <hip/hip_bf16.h>

#define NUSERS  50000
#define NNODES  100000
#define NEDGES  3200000
#define DIM     64
#define OSTRIDE 256   // output row stride: (3+1)*64
#define NBUCK   391   // ceil(NNODES/256) buckets of 256 rows
#define EPB     8192  // edges per block in bucketing kernels
#define NPBLK   391   // ceil(NEDGES/EPB)

typedef unsigned short u16;
typedef unsigned int u32;
typedef __attribute__((ext_vector_type(8))) short bf16x8;
typedef __attribute__((ext_vector_type(4))) float f32x4;

__device__ __forceinline__ float us2f(u16 u) {
    return __uint_as_float((u32)u << 16);
}
__device__ __forceinline__ u16 f2b(float f) {           // f32 -> bf16 RNE bits
    u32 u = __float_as_uint(f);
    return (u16)((u + 0x7fffu + ((u >> 16) & 1u)) >> 16);
}

// ---------------------------------------------------------------------------
// out[:, 0:64] = concat(ue, ie) (fp32); ego[N][64] bf16 full-row
// ---------------------------------------------------------------------------
__global__ __launch_bounds__(256) void init_ego(const float* __restrict__ ue,
                                                const float* __restrict__ ie,
                                                float* __restrict__ out,
                                                u32*   __restrict__ ego32) {
    int gid = blockIdx.x * 256 + threadIdx.x;
    if (gid >= NNODES * 16) return;
    int node = gid >> 4, c = gid & 15;
    float4 v = (node < NUSERS)
        ? ((const float4*)ue)[node * 16 + c]
        : ((const float4*)ie)[(size_t)(node - NUSERS) * 16 + c];
    ((float4*)(out + (size_t)node * OSTRIDE))[c] = v;
    u32* d = ego32 + (size_t)node * 32 + 2 * c;
    d[0] = (u32)f2b(v.x) | ((u32)f2b(v.y) << 16);
    d[1] = (u32)f2b(v.z) | ((u32)f2b(v.w) << 16);
}

// ---------------------------------------------------------------------------
// Bucketed counting sort (R4, proven): count -> scan -> place -> to_csr
// ---------------------------------------------------------------------------
__global__ __launch_bounds__(256) void bucket_count(const int* __restrict__ rows,
                                                    int* __restrict__ bcount) {
    __shared__ int lh[NBUCK];
    int tid = threadIdx.x;
    for (int i = tid; i < NBUCK; i += 256) lh[i] = 0;
    __syncthreads();
    int e0 = blockIdx.x * EPB, e1 = min(e0 + EPB, NEDGES);
    for (int e = e0 + tid; e < e1; e += 256)
        atomicAdd(&lh[rows[e] >> 8], 1);
    __syncthreads();
    for (int i = tid; i < NBUCK; i += 256)
        if (lh[i]) atomicAdd(&bcount[i], lh[i]);
}

__global__ __launch_bounds__(512) void bucket_scan(const int* __restrict__ bcount,
                                                   int* __restrict__ bbase,
                                                   int* __restrict__ bcursor,
                                                   int* __restrict__ rs) {
    __shared__ int sc[512];
    int tid = threadIdx.x;
    int v = (tid < NBUCK) ? bcount[tid] : 0;
    sc[tid] = v;
    __syncthreads();
    for (int off = 1; off < 512; off <<= 1) {
        int t = (tid >= off) ? sc[tid - off] : 0;
        __syncthreads();
        sc[tid] += t;
        __syncthreads();
    }
    if (tid < NBUCK) {
        int excl = sc[tid] - v;
        bbase[tid] = excl;
        bcursor[tid] = excl;
    }
    if (tid == 0) { bbase[NBUCK] = NEDGES; rs[NNODES] = NEDGES; }
}

__global__ __launch_bounds__(256) void bucket_place(const int*   __restrict__ rows,
                                                    const int*   __restrict__ cols,
                                                    const float* __restrict__ vals,
                                                    int*  __restrict__ bcursor,
                                                    int2* __restrict__ tmp) {
    __shared__ int lh[NBUCK];
    int tid = threadIdx.x;
    for (int i = tid; i < NBUCK; i += 256) lh[i] = 0;
    __syncthreads();
    int e0 = blockIdx.x * EPB, e1 = min(e0 + EPB, NEDGES);
    for (int e = e0 + tid; e < e1; e += 256)
        atomicAdd(&lh[rows[e] >> 8], 1);
    __syncthreads();
    for (int i = tid; i < NBUCK; i += 256) {
        int c = lh[i];
        lh[i] = c ? atomicAdd(&bcursor[i], c) : 0;
    }
    __syncthreads();
    for (int e = e0 + tid; e < e1; e += 256) {
        int r = rows[e];
        int p = atomicAdd(&lh[r >> 8], 1);
        tmp[p] = make_int2(((r & 255) << 20) | cols[e], (int)f2b(vals[e]));
    }
}

__global__ __launch_bounds__(256) void bucket_to_csr(const int*  __restrict__ bbase,
                                                     const int2* __restrict__ tmp,
                                                     int* __restrict__ rs,
                                                     int* __restrict__ colS,
                                                     u16* __restrict__ valS) {
    __shared__ int rcnt[256];
    __shared__ int cur[256];
    int b = blockIdx.x, tid = threadIdx.x;
    int j0 = bbase[b], j1 = bbase[b + 1];
    rcnt[tid] = 0;
    __syncthreads();
    for (int j = j0 + tid; j < j1; j += 256)
        atomicAdd(&rcnt[tmp[j].x >> 20], 1);
    __syncthreads();
    int own = rcnt[tid];
    for (int off = 1; off < 256; off <<= 1) {
        int t = (tid >= off) ? rcnt[tid - off] : 0;
        __syncthreads();
        rcnt[tid] += t;
        __syncthreads();
    }
    int start = j0 + rcnt[tid] - own;
    int row = b * 256 + tid;
    if (row < NNODES) rs[row] = start;
    cur[tid] = start;
    __syncthreads();
    for (int j = j0 + tid; j < j1; j += 256) {
        int2 t2 = tmp[j];
        int p = atomicAdd(&cur[t2.x >> 20], 1);
        colS[p] = t2.x & 0xFFFFF;
        valS[p] = (u16)t2.y;
    }
}

// ---------------------------------------------------------------------------
// Pre-convert weights to fragment-ordered bf16 (once per call, 3 layers)
// ---------------------------------------------------------------------------
__global__ __launch_bounds__(256) void weights_prep(const float* __restrict__ Wg,
                                                    const float* __restrict__ Wb,
                                                    u16* __restrict__ wpre) {
    int layer = blockIdx.y;
    int idx = blockIdx.x * 256 + threadIdx.x;   // 0..8191
    int e = idx & 7, l = (idx >> 3) & 63, t = (idx >> 9) & 3, s = idx >> 11;
    int k = 32 * s + 8 * (l >> 4) + e;
    int n = 16 * t + (l & 15);
    float wv = (k < 64) ? Wg[layer * 4096 + k * 64 + n]
                        : Wb[layer * 4096 + (k - 64) * 64 + n];
    wpre[layer * 8192 + idx] = f2b(wv);
}

// ---------------------------------------------------------------------------
// SpMM v3: wave = 1 row; lane = (h, d): h = edge parity, d = dword (2 dims).
// Each gather instruction = u32 x 64 lanes = TWO edges' full 128B rows.
// 8 dual-gathers per iter -> 16 edges in flight. Final shfl_xor(32) merge.
// ---------------------------------------------------------------------------
__global__ __launch_bounds__(256) void spmm(const int* __restrict__ rs,
                                            const int* __restrict__ colS,
                                            const u16* __restrict__ valS,
                                            const u32* __restrict__ ego32,
                                            u32*       __restrict__ side32) {
    int tid = threadIdx.x;
    int w = tid >> 6, lane = tid & 63;
    int h = lane >> 5, d = lane & 31;
    int row = blockIdx.x * 4 + w;
    int j0 = rs[row], j1 = rs[row + 1];

    float alo = 0.f, ahi = 0.f;
    float blo = 0.f, bhi = 0.f;
    int j = j0;
    for (; j + 16 <= j1; j += 16) {
        #pragma unroll
        for (int s = 0; s < 8; ++s) {
            int e = j + 2 * s + h;
            int c = colS[e];
            float v = us2f(valS[e]);
            u32 g = ego32[(size_t)c * 32 + d];
            if (s & 1) {
                blo = fmaf(v, __uint_as_float(g << 16), blo);
                bhi = fmaf(v, __uint_as_float(g & 0xFFFF0000u), bhi);
            } else {
                alo = fmaf(v, __uint_as_float(g << 16), alo);
                ahi = fmaf(v, __uint_as_float(g & 0xFFFF0000u), ahi);
            }
        }
    }
    for (; j < j1; j += 2) {
        int e = j + h;
        if (e < j1) {
            int c = colS[e];
            float v = us2f(valS[e]);
            u32 g = ego32[(size_t)c * 32 + d];
            alo = fmaf(v, __uint_as_float(g << 16), alo);
            ahi = fmaf(v, __uint_as_float(g & 0xFFFF0000u), ahi);
        }
    }
    alo += blo; ahi += bhi;
    alo += __shfl_xor(alo, 32, 64);
    ahi += __shfl_xor(ahi, 32, 64);
    if (h == 0)
        side32[(size_t)row * 32 + d] = (u32)f2b(alo) | ((u32)f2b(ahi) << 16);
}

// ---------------------------------------------------------------------------
// Dense layer via MFMA: C[N,64] = [side | ego_raw*side] @ [Wg; Wb] + bsum,
// leaky-relu; raw fp32 -> out col (layer+1); bf16 -> ego[N][64].
// ---------------------------------------------------------------------------
__global__ __launch_bounds__(256) void dense_mfma(const u16* __restrict__ side,
                                                  float*     __restrict__ out,
                                                  u16*       __restrict__ ego,
                                                  const u16* __restrict__ wpre,
                                                  const float* __restrict__ bg,
                                                  const float* __restrict__ bb,
                                                  int layer) {
    __shared__ u16 bfr[8192];
    __shared__ float lbias[64];

    int tid = threadIdx.x;
    {   // straight 16KB copy of pre-converted weights
        const uint4* src = (const uint4*)(wpre + layer * 8192);
        uint4* dst = (uint4*)bfr;
        #pragma unroll
        for (int i = 0; i < 4; ++i) dst[tid + 256 * i] = src[tid + 256 * i];
    }
    if (tid < 64) lbias[tid] = bg[layer * 64 + tid] + bb[layer * 64 + tid];
    __syncthreads();

    int w = tid >> 6, lane = tid & 63;
    int g = lane >> 4, m = lane & 15;
    int rb = blockIdx.x * 64 + w * 16;
    int rowc = min(rb + m, NNODES - 1);

    bf16x8 sf0 = *(const bf16x8*)(side + (size_t)rowc * DIM + g * 8);
    bf16x8 sf1 = *(const bf16x8*)(side + (size_t)rowc * DIM + 32 + g * 8);
    const float* erow = out + (size_t)rowc * OSTRIDE + layer * DIM;
    float4 e0a = *(const float4*)(erow + 8 * g);
    float4 e0b = *(const float4*)(erow + 8 * g + 4);
    float4 e1a = *(const float4*)(erow + 32 + 8 * g);
    float4 e1b = *(const float4*)(erow + 32 + 8 * g + 4);
    float ev0[8] = {e0a.x, e0a.y, e0a.z, e0a.w, e0b.x, e0b.y, e0b.z, e0b.w};
    float ev1[8] = {e1a.x, e1a.y, e1a.z, e1a.w, e1b.x, e1b.y, e1b.z, e1b.w};
    bf16x8 pf0, pf1;
    #pragma unroll
    for (int e = 0; e < 8; ++e) {
        pf0[e] = (short)f2b(us2f((u16)sf0[e]) * ev0[e]);
        pf1[e] = (short)f2b(us2f((u16)sf1[e]) * ev1[e]);
    }

    const bf16x8* B = (const bf16x8*)bfr;
    f32x4 acc[4];
    #pragma unroll
    for (int t = 0; t < 4; ++t) {
        acc[t] = (f32x4){0.f, 0.f, 0.f, 0.f};
        acc[t] = __builtin_amdgcn_mfma_f32_16x16x32_bf16(sf0, B[(0 * 4 + t) * 64 + lane], acc[t], 0, 0, 0);
        acc[t] = __builtin_amdgcn_mfma_f32_16x16x32_bf16(sf1, B[(1 * 4 + t) * 64 + lane], acc[t], 0, 0, 0);
        acc[t] = __builtin_amdgcn_mfma_f32_16x16x32_bf16(pf0, B[(2 * 4 + t) * 64 + lane], acc[t], 0, 0, 0);
        acc[t] = __builtin_amdgcn_mfma_f32_16x16x32_bf16(pf1, B[(3 * 4 + t) * 64 + lane], acc[t], 0, 0, 0);
    }

    // D col = 16t+m, row = rb + 4g + r
    #pragma unroll
    for (int t = 0; t < 4; ++t) {
        float bsv = lbias[16 * t + m];
        #pragma unroll
        for (int r = 0; r < 4; ++r) {
            int rw = rb + 4 * g + r;
            if (rw < NNODES) {
                float v = acc[t][r] + bsv;
                v = v >= 0.f ? v : 0.2f * v;
                out[(size_t)rw * OSTRIDE + (layer + 1) * DIM + 16 * t + m] = v;
                ego[(size_t)rw * DIM + 16 * t + m] = f2b(v);
            }
        }
    }
}

// ---------------------------------------------------------------------------
// L2-normalize the three layer column blocks (cols 64..255)
// ---------------------------------------------------------------------------
__global__ __launch_bounds__(256) void normalize_cols(float* __restrict__ out) {
    int node = blockIdx.x * 4 + (threadIdx.x >> 6);
    int lane = threadIdx.x & 63;
    float* p = out + (size_t)node * OSTRIDE + DIM;
    #pragma unroll
    for (int b = 0; b < 3; ++b) {
        float v = p[b * 64 + lane];
        float ss = v * v;
        #pragma unroll
        for (int m = 1; m < 64; m <<= 1) ss += __shfl_xor(ss, m, 64);
        p[b * 64 + lane] = v / fmaxf(sqrtf(ss), 1e-12f);
    }
}

// ---------------------------------------------------------------------------
extern "C" void kernel_launch(void* const* d_in, const int* in_sizes, int n_in,
                              void* d_out, int out_size, void* d_ws, size_t ws_size,
                              hipStream_t stream) {
    const float* ue   = (const float*)d_in[0];
    const float* ie   = (const float*)d_in[1];
    const float* Wg   = (const float*)d_in[2];
    const float* bg   = (const float*)d_in[3];
    const float* Wb   = (const float*)d_in[4];
    const float* bb   = (const float*)d_in[5];
    const int*   rows = (const int*)d_in[6];
    const int*   cols = (const int*)d_in[7];
    const float* vals = (const float*)d_in[8];
    float* out = (float*)d_out;

    // ws (45.3 MB): rs[N+1] | colS[E] | valS[E] | bucket meta | wpre[3*8192] |
    // tmp[E] int2 (25.6MB) aliased after CSR build by ego[N*64]u16 + side[N*64]u16
    int* rs   = (int*)d_ws;
    int* colS = rs + NNODES + 1;
    u16* valS = (u16*)(colS + NEDGES);
    int* bcount  = (int*)(valS + NEDGES);
    int* bbase   = bcount + NBUCK;
    int* bcursor = bbase + NBUCK + 1;
    u16* wpre    = (u16*)(bcursor + NBUCK);
    uintptr_t tp = ((uintptr_t)(wpre + 3 * 8192) + 15) & ~(uintptr_t)15;
    int2* tmp = (int2*)tp;
    u32*  ego32 = (u32*)tp;                             // 12.8 MB
    u16*  side  = (u16*)(ego32 + (size_t)NNODES * 32);  // 12.8 MB

    hipMemsetAsync(bcount, 0, NBUCK * sizeof(int), stream);
    bucket_count<<<NPBLK, 256, 0, stream>>>(rows, bcount);
    bucket_scan<<<1, 512, 0, stream>>>(bcount, bbase, bcursor, rs);
    bucket_place<<<NPBLK, 256, 0, stream>>>(rows, cols, vals, bcursor, tmp);
    bucket_to_csr<<<NBUCK, 256, 0, stream>>>(bbase, tmp, rs, colS, valS);

    weights_prep<<<dim3(32, 3), 256, 0, stream>>>(Wg, Wb, wpre);

    // init_ego AFTER the sort: ego32 aliases tmp
    init_ego<<<(NNODES * 16 + 255) / 256, 256, 0, stream>>>(ue, ie, out, ego32);

    for (int l = 0; l < 3; ++l) {
        spmm<<<NNODES / 4, 256, 0, stream>>>(rs, colS, valS, ego32, (u32*)side);
        dense_mfma<<<(NNODES + 63) / 64, 256, 0, stream>>>(side, out, (u16*)ego32,
                                                           wpre, bg, bb, l);
    }

    normalize_cols<<<NNODES / 4, 256, 0, stream>>>(out);
}